// Round 4
// baseline (718.625 us; speedup 1.0000x reference)
//
#include <hip/hip_runtime.h>

// ---------------- problem constants ----------------
#define B_   4
#define T_   2048
#define C_   1024
#define NH_  16
#define HS_  64
#define N1_  3072      // 3*C

typedef __attribute__((ext_vector_type(8))) short short8;   // 8 bf16 (4 VGPRs)
typedef __attribute__((ext_vector_type(4))) float f32x4;

__device__ __forceinline__ short f2bf(float f) {   // RNE
  unsigned u = __float_as_uint(f);
  unsigned r = (u + 0x7fffu + ((u >> 16) & 1u)) >> 16;
  return (short)r;
}
__device__ __forceinline__ float clampf(float v) {
  return fminf(fmaxf(v, -60000.0f), 60000.0f);   // NaN -> finite; diagnostic
}

// async global->LDS, 16B per lane (dest = wave-uniform base + lane*16)
typedef __attribute__((address_space(1))) unsigned int as1_uint;
typedef __attribute__((address_space(3))) unsigned int as3_uint;
__device__ __forceinline__ void g2l16(const void* g, void* l) {
  __builtin_amdgcn_global_load_lds((as1_uint*)g, (as3_uint*)l, 16, 0, 0);
}

// ============================================================
// f32 -> bf16 conversion, 8 elements/thread, n % 2048 == 0
// ============================================================
__global__ __launch_bounds__(256) void conv_bf16(
    const float* __restrict__ src, short* __restrict__ dst)
{
  const size_t i = ((size_t)blockIdx.x * 256 + threadIdx.x) * 8;
  const f32x4 a = *(const f32x4*)&src[i];
  const f32x4 b = *(const f32x4*)&src[i + 4];
  short8 o;
  o[0] = f2bf(a[0]); o[1] = f2bf(a[1]); o[2] = f2bf(a[2]); o[3] = f2bf(a[3]);
  o[4] = f2bf(b[0]); o[5] = f2bf(b[1]); o[6] = f2bf(b[2]); o[7] = f2bf(b[3]);
  *(short8*)&dst[i] = o;
}

// ============================================================
// Per-batch QKV GEMM: qkv = x_b @ Wqkv^T + bqkv (bias f32)
// X (bf16) [T_, C_]; scatter into Q/K/V [NH_, T_, HS_] (bf16).
// 128x128 tile, BK=32, 256 threads (4 waves, 2x2 of 64x64)
// ============================================================
__global__ __launch_bounds__(256) void qkv_gemm_b(
    const short* __restrict__ X,    // [T_, C_] bf16
    const short* __restrict__ W,    // [N1_, C_] bf16
    const float* __restrict__ bias, // [N1_] f32
    short* __restrict__ Qo, short* __restrict__ Ko, short* __restrict__ Vo)
{
  __shared__ short As[128 * 32];
  __shared__ short Bs[128 * 32];
  const int tid = threadIdx.x;
  const int lane = tid & 63;
  const int wid = tid >> 6;
  const int wy = wid >> 1, wx = wid & 1;
  const int lq = lane >> 4, lm = lane & 15;
  const int row0 = blockIdx.x * 128;
  const int col0 = blockIdx.y * 128;

  f32x4 acc[4][4] = {};

  const int c0 = tid, c1 = tid + 256;
  const int ar0 = c0 >> 2, ak0 = (c0 & 3) << 3;
  const int ar1 = c1 >> 2, ak1 = (c1 & 3) << 3;

  for (int k0 = 0; k0 < C_; k0 += 32) {
    __syncthreads();
    g2l16(&X[(size_t)(row0 + ar0) * C_ + k0 + ak0], &As[c0 * 8]);
    g2l16(&X[(size_t)(row0 + ar1) * C_ + k0 + ak1], &As[c1 * 8]);
    g2l16(&W[(size_t)(col0 + ar0) * C_ + k0 + ak0], &Bs[c0 * 8]);
    g2l16(&W[(size_t)(col0 + ar1) * C_ + k0 + ak1], &Bs[c1 * 8]);
    __syncthreads();

    short8 af[4], bfr[4];
#pragma unroll
    for (int mi = 0; mi < 4; ++mi)
      af[mi] = *(const short8*)&As[(wy * 64 + mi * 16 + lm) * 32 + lq * 8];
#pragma unroll
    for (int ni = 0; ni < 4; ++ni)
      bfr[ni] = *(const short8*)&Bs[(wx * 64 + ni * 16 + lm) * 32 + lq * 8];
#pragma unroll
    for (int mi = 0; mi < 4; ++mi)
#pragma unroll
      for (int ni = 0; ni < 4; ++ni)
        acc[mi][ni] = __builtin_amdgcn_mfma_f32_16x16x32_bf16(af[mi], bfr[ni], acc[mi][ni], 0, 0, 0);
  }

#pragma unroll
  for (int ni = 0; ni < 4; ++ni) {
    const int n = col0 + wx * 64 + ni * 16 + lm;
    const float bv = bias[n];
    const int sel = n >> 10;              // 0=Q, 1=K, 2=V
    const int cc = n & (C_ - 1);
    const int h = cc >> 6, d = cc & 63;
    short* dst = (sel == 0) ? Qo : (sel == 1) ? Ko : Vo;
#pragma unroll
    for (int mi = 0; mi < 4; ++mi) {
#pragma unroll
      for (int i = 0; i < 4; ++i) {
        const int t = row0 + wy * 64 + mi * 16 + lq * 4 + i;
        dst[(size_t)(h * T_ + t) * HS_ + d] = f2bf(clampf(acc[mi][ni][i] + bv));
      }
    }
  }
}

// ============================================================
// Per-batch proj GEMM: out_b = Y_b @ Wproj^T + bproj  -> FLOAT32 out
// ============================================================
__global__ __launch_bounds__(256) void proj_gemm_b(
    const short* __restrict__ Y,    // [T_, C_] bf16
    const short* __restrict__ W,    // [C_, C_] bf16
    const float* __restrict__ bias, // [C_] f32
    float* __restrict__ Out)        // [T_, C_] f32
{
  __shared__ short As[128 * 32];
  __shared__ short Bs[128 * 32];
  const int tid = threadIdx.x;
  const int lane = tid & 63;
  const int wid = tid >> 6;
  const int wy = wid >> 1, wx = wid & 1;
  const int lq = lane >> 4, lm = lane & 15;
  const int row0 = blockIdx.x * 128;
  const int col0 = blockIdx.y * 128;

  f32x4 acc[4][4] = {};

  const int c0 = tid, c1 = tid + 256;
  const int ar0 = c0 >> 2, ak0 = (c0 & 3) << 3;
  const int ar1 = c1 >> 2, ak1 = (c1 & 3) << 3;

  for (int k0 = 0; k0 < C_; k0 += 32) {
    __syncthreads();
    g2l16(&Y[(size_t)(row0 + ar0) * C_ + k0 + ak0], &As[c0 * 8]);
    g2l16(&Y[(size_t)(row0 + ar1) * C_ + k0 + ak1], &As[c1 * 8]);
    g2l16(&W[(size_t)(col0 + ar0) * C_ + k0 + ak0], &Bs[c0 * 8]);
    g2l16(&W[(size_t)(col0 + ar1) * C_ + k0 + ak1], &Bs[c1 * 8]);
    __syncthreads();

    short8 af[4], bfr[4];
#pragma unroll
    for (int mi = 0; mi < 4; ++mi)
      af[mi] = *(const short8*)&As[(wy * 64 + mi * 16 + lm) * 32 + lq * 8];
#pragma unroll
    for (int ni = 0; ni < 4; ++ni)
      bfr[ni] = *(const short8*)&Bs[(wx * 64 + ni * 16 + lm) * 32 + lq * 8];
#pragma unroll
    for (int mi = 0; mi < 4; ++mi)
#pragma unroll
      for (int ni = 0; ni < 4; ++ni)
        acc[mi][ni] = __builtin_amdgcn_mfma_f32_16x16x32_bf16(af[mi], bfr[ni], acc[mi][ni], 0, 0, 0);
  }

#pragma unroll
  for (int ni = 0; ni < 4; ++ni) {
    const int n = col0 + wx * 64 + ni * 16 + lm;
    const float bv = bias[n];
#pragma unroll
    for (int mi = 0; mi < 4; ++mi) {
#pragma unroll
      for (int i = 0; i < 4; ++i) {
        const int m = row0 + wy * 64 + mi * 16 + lq * 4 + i;
        Out[(size_t)m * C_ + n] = clampf(acc[mi][ni][i] + bv);
      }
    }
  }
}

// ============================================================
// Per-batch flash attention: block = (h, 64 q-rows), 4 waves x 16 q-rows.
// Q/K/V: [NH_, T_, HS_] bf16. Writes Y_b [T_, C_] bf16 (col = h*64+d).
// ============================================================
__global__ __launch_bounds__(256) void attn_b(
    const short* __restrict__ Qg, const short* __restrict__ Kg,
    const short* __restrict__ Vg, short* __restrict__ Yo)
{
  __shared__ short Ks[64 * 64];
  __shared__ short Vt[64 * 64];      // transposed: Vt[hs][kv]
  __shared__ short Ps[4][16 * 64];   // per-wave P tile

  const int tid = threadIdx.x;
  const int lane = tid & 63;
  const int w = tid >> 6;
  const int lq = lane >> 4, lm = lane & 15;
  const int h = blockIdx.y;
  const int qt = blockIdx.x;
  const int q0 = qt * 64;
  const size_t base = (size_t)h * T_ * HS_;

  const int qrow = q0 + w * 16 + lm;
  const short8 qf0 = *(const short8*)&Qg[base + (size_t)qrow * HS_ + lq * 8];
  const short8 qf1 = *(const short8*)&Qg[base + (size_t)qrow * HS_ + 32 + lq * 8];

  float m_run[4], l_run[4];
  f32x4 o_acc[4] = {};
#pragma unroll
  for (int i = 0; i < 4; ++i) { m_run[i] = -3.0e38f; l_run[i] = 0.0f; }

  const float sf = 0.125f * 1.44269504089f;  // 1/sqrt(HS) * log2(e)

  const int c0 = tid, c1 = tid + 256;
  const int r0 = c0 >> 3, h0 = (c0 & 7) << 3;
  const int r1 = c1 >> 3, h1 = (c1 & 7) << 3;

  for (int kt = 0; kt <= qt; ++kt) {
    const int kv0 = kt * 64;
    __syncthreads();
    g2l16(&Kg[base + (size_t)(kv0 + r0) * HS_ + h0], &Ks[c0 * 8]);
    g2l16(&Kg[base + (size_t)(kv0 + r1) * HS_ + h1], &Ks[c1 * 8]);
    {
      union { short8 v; short s[8]; } va, vb;
      va.v = *(const short8*)&Vg[base + (size_t)(kv0 + r0) * HS_ + h0];
      vb.v = *(const short8*)&Vg[base + (size_t)(kv0 + r1) * HS_ + h1];
#pragma unroll
      for (int j = 0; j < 8; ++j) Vt[(h0 + j) * 64 + r0] = va.s[j];
#pragma unroll
      for (int j = 0; j < 8; ++j) Vt[(h1 + j) * 64 + r1] = vb.s[j];
    }
    __syncthreads();

    // ---- S = Q K^T ----
    f32x4 sv[4];
#pragma unroll
    for (int ni = 0; ni < 4; ++ni) {
      const short8 kf0 = *(const short8*)&Ks[(ni * 16 + lm) * 64 + lq * 8];
      const short8 kf1 = *(const short8*)&Ks[(ni * 16 + lm) * 64 + 32 + lq * 8];
      f32x4 s = {};
      s = __builtin_amdgcn_mfma_f32_16x16x32_bf16(qf0, kf0, s, 0, 0, 0);
      s = __builtin_amdgcn_mfma_f32_16x16x32_bf16(qf1, kf1, s, 0, 0, 0);
      sv[ni] = s * sf;
    }

    if (kt == qt) {
#pragma unroll
      for (int ni = 0; ni < 4; ++ni) {
        const int kvc = kv0 + ni * 16 + lm;
#pragma unroll
        for (int i = 0; i < 4; ++i) {
          const int qr = q0 + w * 16 + lq * 4 + i;
          if (kvc > qr) sv[ni][i] = -3.0e38f;
        }
      }
    }
#pragma unroll
    for (int ni = 0; ni < 4; ++ni)
#pragma unroll
      for (int i = 0; i < 4; ++i)
        sv[ni][i] = fminf(sv[ni][i], 60000.0f);

    // ---- online softmax ----
    float alpha[4];
#pragma unroll
    for (int i = 0; i < 4; ++i) {
      float v = fmaxf(fmaxf(sv[0][i], sv[1][i]), fmaxf(sv[2][i], sv[3][i]));
      v = fmaxf(v, __shfl_xor(v, 1));
      v = fmaxf(v, __shfl_xor(v, 2));
      v = fmaxf(v, __shfl_xor(v, 4));
      v = fmaxf(v, __shfl_xor(v, 8));
      const float mnew = fmaxf(m_run[i], v);
      alpha[i] = exp2f(m_run[i] - mnew);
      m_run[i] = mnew;
    }
#pragma unroll
    for (int ni = 0; ni < 4; ++ni)
#pragma unroll
      for (int i = 0; i < 4; ++i)
        sv[ni][i] = exp2f(sv[ni][i] - m_run[i]);
#pragma unroll
    for (int i = 0; i < 4; ++i) {
      float ps = sv[0][i] + sv[1][i] + sv[2][i] + sv[3][i];
      ps += __shfl_xor(ps, 1);
      ps += __shfl_xor(ps, 2);
      ps += __shfl_xor(ps, 4);
      ps += __shfl_xor(ps, 8);
      l_run[i] = l_run[i] * alpha[i] + ps;
    }
#pragma unroll
    for (int d = 0; d < 4; ++d)
#pragma unroll
      for (int i = 0; i < 4; ++i)
        o_acc[d][i] *= alpha[i];

    // ---- P: C-layout -> A-layout via per-wave LDS ----
#pragma unroll
    for (int ni = 0; ni < 4; ++ni)
#pragma unroll
      for (int i = 0; i < 4; ++i)
        Ps[w][(lq * 4 + i) * 64 + ni * 16 + lm] = f2bf(sv[ni][i]);

    const short8 pf0 = *(const short8*)&Ps[w][lm * 64 + lq * 8];
    const short8 pf1 = *(const short8*)&Ps[w][lm * 64 + 32 + lq * 8];
#pragma unroll
    for (int di = 0; di < 4; ++di) {
      const short8 vf0 = *(const short8*)&Vt[(di * 16 + lm) * 64 + lq * 8];
      const short8 vf1 = *(const short8*)&Vt[(di * 16 + lm) * 64 + 32 + lq * 8];
      o_acc[di] = __builtin_amdgcn_mfma_f32_16x16x32_bf16(pf0, vf0, o_acc[di], 0, 0, 0);
      o_acc[di] = __builtin_amdgcn_mfma_f32_16x16x32_bf16(pf1, vf1, o_acc[di], 0, 0, 0);
    }
  }

  // ---- epilogue: normalize, store to Y_b [T_, C_] bf16 ----
#pragma unroll
  for (int i = 0; i < 4; ++i) {
    const float rl = 1.0f / l_run[i];
    const int t = q0 + w * 16 + lq * 4 + i;
    const size_t rowo = (size_t)t * C_ + h * HS_;
#pragma unroll
    for (int di = 0; di < 4; ++di)
      Yo[rowo + di * 16 + lm] = f2bf(clampf(o_acc[di][i] * rl));
  }
}

// ============================================================
extern "C" void kernel_launch(void* const* d_in, const int* in_sizes, int n_in,
                              void* d_out, int out_size, void* d_ws, size_t ws_size,
                              hipStream_t stream) {
  (void)in_sizes; (void)n_in; (void)out_size; (void)ws_size;
  const float* x     = (const float*)d_in[0];   // [B,T,C] f32
  const float* Wqkv  = (const float*)d_in[1];   // [3C,C]  f32
  const float* bqkv  = (const float*)d_in[2];   // [3C]    f32
  const float* Wproj = (const float*)d_in[3];   // [C,C]   f32
  const float* bproj = (const float*)d_in[4];   // [C]     f32
  float* out = (float*)d_out;                   // [B,T,C] f32

  // ws (bf16 elements): Wqkv_bf | Wproj_bf | S0 (x_bf then Y) | Q | K | V
  const size_t nWq = (size_t)N1_ * C_;          // 3,145,728
  const size_t nWp = (size_t)C_ * C_;           // 1,048,576
  const size_t perb = (size_t)T_ * C_;          // 2,097,152 (= NH*T*HS)
  short* Wq_bf = (short*)d_ws;
  short* Wp_bf = Wq_bf + nWq;
  short* S0    = Wp_bf + nWp;                   // x_bf, later Y
  short* Qw    = S0 + perb;
  short* Kw    = Qw + perb;
  short* Vw    = Kw + perb;                     // total 25.2 MB

  dim3 blk(256);
  conv_bf16<<<dim3((int)(nWq / 2048)), blk, 0, stream>>>(Wqkv, Wq_bf);
  conv_bf16<<<dim3((int)(nWp / 2048)), blk, 0, stream>>>(Wproj, Wp_bf);

  for (int b = 0; b < B_; ++b) {
    const float* xb = x   + (size_t)b * perb;
    float*       ob = out + (size_t)b * perb;
    conv_bf16<<<dim3((int)(perb / 2048)), blk, 0, stream>>>(xb, S0);
    qkv_gemm_b<<<dim3(T_ / 128, N1_ / 128), blk, 0, stream>>>(S0, Wq_bf, bqkv, Qw, Kw, Vw);
    attn_b<<<dim3(T_ / 64, NH_), blk, 0, stream>>>(Qw, Kw, Vw, S0);
    proj_gemm_b<<<dim3(T_ / 128, C_ / 128), blk, 0, stream>>>(S0, Wp_bf, bproj, ob);
  }
}

// Round 5
// 461.695 us; speedup vs baseline: 1.5565x; 1.5565x over previous
//
#include <hip/hip_runtime.h>

// ---------------- problem constants ----------------
#define B_   4
#define T_   2048
#define C_   1024
#define NH_  16
#define HS_  64
#define M_   8192      // B*T
#define N1_  3072      // 3*C
#define BH_  64        // B*NH

typedef __attribute__((ext_vector_type(8))) short short8;   // 8 bf16
typedef __attribute__((ext_vector_type(4))) short short4v;  // 4 bf16
typedef __attribute__((ext_vector_type(4))) float f32x4;

__device__ __forceinline__ short f2bf(float f) {   // RNE
  unsigned u = __float_as_uint(f);
  unsigned r = (u + 0x7fffu + ((u >> 16) & 1u)) >> 16;
  return (short)r;
}
__device__ __forceinline__ float clampf(float v) {
  return fminf(fmaxf(v, -60000.0f), 60000.0f);
}

// async global->LDS, 16B per lane (dest = wave-uniform base + lane*16)
typedef __attribute__((address_space(1))) unsigned int as1_uint;
typedef __attribute__((address_space(3))) unsigned int as3_uint;
__device__ __forceinline__ void g2l16(const void* g, void* l) {
  __builtin_amdgcn_global_load_lds((as1_uint*)g, (as3_uint*)l, 16, 0, 0);
}

// ============================================================
// f32 -> bf16, 8 elements/thread, n % 2048 == 0
// ============================================================
__global__ __launch_bounds__(256) void conv_bf16(
    const float* __restrict__ src, short* __restrict__ dst)
{
  const size_t i = ((size_t)blockIdx.x * 256 + threadIdx.x) * 8;
  const f32x4 a = *(const f32x4*)&src[i];
  const f32x4 b = *(const f32x4*)&src[i + 4];
  short8 o;
  o[0] = f2bf(a[0]); o[1] = f2bf(a[1]); o[2] = f2bf(a[2]); o[3] = f2bf(a[3]);
  o[4] = f2bf(b[0]); o[5] = f2bf(b[1]); o[6] = f2bf(b[2]); o[7] = f2bf(b[3]);
  *(short8*)&dst[i] = o;
}

// ============================================================
// QKV GEMM (grid = (M/128, 24)): qkv = X @ Wqkv^T + bqkv
// X [M,C] bf16. Q,K -> [BH][T][HS]; V -> TRANSPOSED [BH][HS][T].
// For per-batch use, pass M=2048 buffers (bh = h).
// ============================================================
__global__ __launch_bounds__(256) void qkv_gemm(
    const short* __restrict__ X,    // [M, C] bf16
    const short* __restrict__ W,    // [N1, C] bf16
    const float* __restrict__ bias, // [N1] f32
    short* __restrict__ Qo, short* __restrict__ Ko, short* __restrict__ Vt)
{
  __shared__ short As[128 * 32];
  __shared__ short Bs[128 * 32];
  const int tid = threadIdx.x;
  const int lane = tid & 63;
  const int wid = tid >> 6;
  const int wy = wid >> 1, wx = wid & 1;
  const int lq = lane >> 4, lm = lane & 15;
  const int row0 = blockIdx.x * 128;
  const int col0 = blockIdx.y * 128;

  f32x4 acc[4][4] = {};

  const int c0 = tid, c1 = tid + 256;
  const int ar0 = c0 >> 2, ak0 = (c0 & 3) << 3;
  const int ar1 = c1 >> 2, ak1 = (c1 & 3) << 3;

  for (int k0 = 0; k0 < C_; k0 += 32) {
    __syncthreads();
    g2l16(&X[(size_t)(row0 + ar0) * C_ + k0 + ak0], &As[c0 * 8]);
    g2l16(&X[(size_t)(row0 + ar1) * C_ + k0 + ak1], &As[c1 * 8]);
    g2l16(&W[(size_t)(col0 + ar0) * C_ + k0 + ak0], &Bs[c0 * 8]);
    g2l16(&W[(size_t)(col0 + ar1) * C_ + k0 + ak1], &Bs[c1 * 8]);
    __syncthreads();

    short8 af[4], bfr[4];
#pragma unroll
    for (int mi = 0; mi < 4; ++mi)
      af[mi] = *(const short8*)&As[(wy * 64 + mi * 16 + lm) * 32 + lq * 8];
#pragma unroll
    for (int ni = 0; ni < 4; ++ni)
      bfr[ni] = *(const short8*)&Bs[(wx * 64 + ni * 16 + lm) * 32 + lq * 8];
#pragma unroll
    for (int mi = 0; mi < 4; ++mi)
#pragma unroll
      for (int ni = 0; ni < 4; ++ni)
        acc[mi][ni] = __builtin_amdgcn_mfma_f32_16x16x32_bf16(af[mi], bfr[ni], acc[mi][ni], 0, 0, 0);
  }

#pragma unroll
  for (int ni = 0; ni < 4; ++ni) {
    const int n = col0 + wx * 64 + ni * 16 + lm;
    const float bv = bias[n];
    const int sel = n >> 10;              // 0=Q, 1=K, 2=V (uniform per tile)
    const int cc = n & (C_ - 1);
    const int h = cc >> 6, d = cc & 63;
    if (sel == 2) {
      // V transposed: Vt[(bh*64 + d)*T + t], 4 consecutive t per lane
#pragma unroll
      for (int mi = 0; mi < 4; ++mi) {
        const int m0 = row0 + wy * 64 + mi * 16 + lq * 4;
        const int b = m0 >> 11, t0 = m0 & (T_ - 1);
        const int bh = b * NH_ + h;
        short4v o;
#pragma unroll
        for (int i = 0; i < 4; ++i) o[i] = f2bf(clampf(acc[mi][ni][i] + bv));
        *(short4v*)&Vt[((size_t)bh * HS_ + d) * T_ + t0] = o;
      }
    } else {
      short* dst = (sel == 0) ? Qo : Ko;
#pragma unroll
      for (int mi = 0; mi < 4; ++mi) {
#pragma unroll
        for (int i = 0; i < 4; ++i) {
          const int m = row0 + wy * 64 + mi * 16 + lq * 4 + i;
          const int b = m >> 11, t = m & (T_ - 1);
          const int bh = b * NH_ + h;
          dst[((size_t)bh * T_ + t) * HS_ + d] = f2bf(clampf(acc[mi][ni][i] + bv));
        }
      }
    }
  }
}

// ============================================================
// Proj GEMM (grid = (M/128, 8)): out = Y @ Wproj^T + bproj -> f32
// ============================================================
__global__ __launch_bounds__(256) void proj_gemm(
    const short* __restrict__ Y,    // [M, C] bf16
    const short* __restrict__ W,    // [C, C] bf16
    const float* __restrict__ bias, // [C] f32
    float* __restrict__ Out)        // [M, C] f32
{
  __shared__ short As[128 * 32];
  __shared__ short Bs[128 * 32];
  const int tid = threadIdx.x;
  const int lane = tid & 63;
  const int wid = tid >> 6;
  const int wy = wid >> 1, wx = wid & 1;
  const int lq = lane >> 4, lm = lane & 15;
  const int row0 = blockIdx.x * 128;
  const int col0 = blockIdx.y * 128;

  f32x4 acc[4][4] = {};

  const int c0 = tid, c1 = tid + 256;
  const int ar0 = c0 >> 2, ak0 = (c0 & 3) << 3;
  const int ar1 = c1 >> 2, ak1 = (c1 & 3) << 3;

  for (int k0 = 0; k0 < C_; k0 += 32) {
    __syncthreads();
    g2l16(&Y[(size_t)(row0 + ar0) * C_ + k0 + ak0], &As[c0 * 8]);
    g2l16(&Y[(size_t)(row0 + ar1) * C_ + k0 + ak1], &As[c1 * 8]);
    g2l16(&W[(size_t)(col0 + ar0) * C_ + k0 + ak0], &Bs[c0 * 8]);
    g2l16(&W[(size_t)(col0 + ar1) * C_ + k0 + ak1], &Bs[c1 * 8]);
    __syncthreads();

    short8 af[4], bfr[4];
#pragma unroll
    for (int mi = 0; mi < 4; ++mi)
      af[mi] = *(const short8*)&As[(wy * 64 + mi * 16 + lm) * 32 + lq * 8];
#pragma unroll
    for (int ni = 0; ni < 4; ++ni)
      bfr[ni] = *(const short8*)&Bs[(wx * 64 + ni * 16 + lm) * 32 + lq * 8];
#pragma unroll
    for (int mi = 0; mi < 4; ++mi)
#pragma unroll
      for (int ni = 0; ni < 4; ++ni)
        acc[mi][ni] = __builtin_amdgcn_mfma_f32_16x16x32_bf16(af[mi], bfr[ni], acc[mi][ni], 0, 0, 0);
  }

#pragma unroll
  for (int ni = 0; ni < 4; ++ni) {
    const int n = col0 + wx * 64 + ni * 16 + lm;
    const float bv = bias[n];
#pragma unroll
    for (int mi = 0; mi < 4; ++mi) {
#pragma unroll
      for (int i = 0; i < 4; ++i) {
        const int m = row0 + wy * 64 + mi * 16 + lq * 4 + i;
        Out[(size_t)m * C_ + n] = clampf(acc[mi][ni][i] + bv);
      }
    }
  }
}

// ============================================================
// Flash attention (grid = (32, BH)): block = (bh, 64 q-rows).
// Q,K: [BH][T][HS]; Vt: [BH][HS][T]  (all bf16).
// Y out: [B][T][C] bf16 at col h*64+d  (BH<=16 => b=0, per-batch mode).
// qt reversed so longest blocks dispatch first.
// ============================================================
#define PS_LD 72   // Ps row stride (shorts): 144B rows keep b128 reads aligned
__global__ __launch_bounds__(256) void attn(
    const short* __restrict__ Qg, const short* __restrict__ Kg,
    const short* __restrict__ Vg, short* __restrict__ Yo)
{
  __shared__ short Ks[64 * 64];
  __shared__ short Vts[64 * 64];        // [d][kv-window]
  __shared__ short Ps[4][16 * PS_LD];   // per-wave P tile

  const int tid = threadIdx.x;
  const int lane = tid & 63;
  const int w = tid >> 6;
  const int lq = lane >> 4, lm = lane & 15;
  const int bh = blockIdx.y;
  const int qt = (gridDim.x - 1) - blockIdx.x;   // long blocks first
  const int q0 = qt * 64;
  const size_t base = (size_t)bh * T_ * HS_;     // same offset for Q,K,Vt

  const int qrow = q0 + w * 16 + lm;
  const short8 qf0 = *(const short8*)&Qg[base + (size_t)qrow * HS_ + lq * 8];
  const short8 qf1 = *(const short8*)&Qg[base + (size_t)qrow * HS_ + 32 + lq * 8];

  float m_run[4], l_run[4];
  f32x4 o_acc[4] = {};
#pragma unroll
  for (int i = 0; i < 4; ++i) { m_run[i] = -3.0e38f; l_run[i] = 0.0f; }

  const float sf = 0.125f * 1.44269504089f;  // 1/sqrt(HS) * log2(e)

  // staging maps: chunk c -> K row r=c>>3, off (c&7)*8 ; Vt row d=c>>3, off (c&7)*8
  const int c0 = tid, c1 = tid + 256;
  const int r0 = c0 >> 3, o0 = (c0 & 7) << 3;
  const int r1 = c1 >> 3, o1 = (c1 & 7) << 3;

  for (int kt = 0; kt <= qt; ++kt) {
    const int kv0 = kt * 64;
    __syncthreads();
    g2l16(&Kg[base + (size_t)(kv0 + r0) * HS_ + o0], &Ks[c0 * 8]);
    g2l16(&Kg[base + (size_t)(kv0 + r1) * HS_ + o1], &Ks[c1 * 8]);
    g2l16(&Vg[base + (size_t)r0 * T_ + kv0 + o0], &Vts[c0 * 8]);
    g2l16(&Vg[base + (size_t)r1 * T_ + kv0 + o1], &Vts[c1 * 8]);
    __syncthreads();

    // ---- S = Q K^T (C-layout: row=lq*4+i, col=ni*16+lm) ----
    f32x4 sv[4];
#pragma unroll
    for (int ni = 0; ni < 4; ++ni) {
      const short8 kf0 = *(const short8*)&Ks[(ni * 16 + lm) * 64 + lq * 8];
      const short8 kf1 = *(const short8*)&Ks[(ni * 16 + lm) * 64 + 32 + lq * 8];
      f32x4 s = {};
      s = __builtin_amdgcn_mfma_f32_16x16x32_bf16(qf0, kf0, s, 0, 0, 0);
      s = __builtin_amdgcn_mfma_f32_16x16x32_bf16(qf1, kf1, s, 0, 0, 0);
      sv[ni] = s * sf;
    }

    if (kt == qt) {   // causal mask on diagonal tile
#pragma unroll
      for (int ni = 0; ni < 4; ++ni) {
        const int kvc = kv0 + ni * 16 + lm;
#pragma unroll
        for (int i = 0; i < 4; ++i) {
          const int qr = q0 + w * 16 + lq * 4 + i;
          if (kvc > qr) sv[ni][i] = -3.0e38f;
        }
      }
    }

    // ---- online softmax (row reduction within 16-lane groups) ----
    float alpha[4];
#pragma unroll
    for (int i = 0; i < 4; ++i) {
      float v = fmaxf(fmaxf(sv[0][i], sv[1][i]), fmaxf(sv[2][i], sv[3][i]));
      v = fmaxf(v, __shfl_xor(v, 1));
      v = fmaxf(v, __shfl_xor(v, 2));
      v = fmaxf(v, __shfl_xor(v, 4));
      v = fmaxf(v, __shfl_xor(v, 8));
      const float mnew = fmaxf(m_run[i], v);
      alpha[i] = exp2f(m_run[i] - mnew);
      m_run[i] = mnew;
    }
#pragma unroll
    for (int ni = 0; ni < 4; ++ni)
#pragma unroll
      for (int i = 0; i < 4; ++i)
        sv[ni][i] = exp2f(sv[ni][i] - m_run[i]);
#pragma unroll
    for (int i = 0; i < 4; ++i) {
      float ps = sv[0][i] + sv[1][i] + sv[2][i] + sv[3][i];
      ps += __shfl_xor(ps, 1);
      ps += __shfl_xor(ps, 2);
      ps += __shfl_xor(ps, 4);
      ps += __shfl_xor(ps, 8);
      l_run[i] = l_run[i] * alpha[i] + ps;
    }
#pragma unroll
    for (int d = 0; d < 4; ++d)
#pragma unroll
      for (int i = 0; i < 4; ++i)
        o_acc[d][i] *= alpha[i];

    // ---- P: C-layout -> A-layout via per-wave LDS ----
#pragma unroll
    for (int ni = 0; ni < 4; ++ni)
#pragma unroll
      for (int i = 0; i < 4; ++i)
        Ps[w][(lq * 4 + i) * PS_LD + ni * 16 + lm] = f2bf(sv[ni][i]);

    const short8 pf0 = *(const short8*)&Ps[w][lm * PS_LD + lq * 8];
    const short8 pf1 = *(const short8*)&Ps[w][lm * PS_LD + 32 + lq * 8];
#pragma unroll
    for (int di = 0; di < 4; ++di) {
      const short8 vf0 = *(const short8*)&Vts[(di * 16 + lm) * 64 + lq * 8];
      const short8 vf1 = *(const short8*)&Vts[(di * 16 + lm) * 64 + 32 + lq * 8];
      o_acc[di] = __builtin_amdgcn_mfma_f32_16x16x32_bf16(pf0, vf0, o_acc[di], 0, 0, 0);
      o_acc[di] = __builtin_amdgcn_mfma_f32_16x16x32_bf16(pf1, vf1, o_acc[di], 0, 0, 0);
    }
  }

  // ---- epilogue: normalize, store Y bf16 [.,T,C] ----
  const int b = bh >> 4, h = bh & 15;
#pragma unroll
  for (int i = 0; i < 4; ++i) {
    const float rl = 1.0f / l_run[i];
    const int t = q0 + w * 16 + lq * 4 + i;
    const size_t rowo = ((size_t)(b * T_ + t)) * C_ + h * HS_;
#pragma unroll
    for (int di = 0; di < 4; ++di)
      Yo[rowo + di * 16 + lm] = f2bf(clampf(o_acc[di][i] * rl));
  }
}

// ============================================================
extern "C" void kernel_launch(void* const* d_in, const int* in_sizes, int n_in,
                              void* d_out, int out_size, void* d_ws, size_t ws_size,
                              hipStream_t stream) {
  (void)in_sizes; (void)n_in; (void)out_size;
  const float* x     = (const float*)d_in[0];
  const float* Wqkv  = (const float*)d_in[1];
  const float* bqkv  = (const float*)d_in[2];
  const float* Wproj = (const float*)d_in[3];
  const float* bproj = (const float*)d_in[4];
  float* out = (float*)d_out;

  const size_t nWq = (size_t)N1_ * C_;        // 3,145,728
  const size_t nWp = (size_t)C_ * C_;         // 1,048,576
  const size_t nFull = (size_t)M_ * C_;       // 8,388,608
  const size_t nB = (size_t)T_ * C_;          // 2,097,152 per batch

  dim3 blk(256);
  const size_t need_batched = (nWq + nWp + 4 * nFull) * sizeof(short); // 75.6 MB

  if (ws_size >= need_batched) {
    // -------- fully batched pipeline --------
    short* Wq_bf = (short*)d_ws;
    short* Wp_bf = Wq_bf + nWq;
    short* S0    = Wp_bf + nWp;      // x_bf, later Y
    short* Qw    = S0 + nFull;
    short* Kw    = Qw + nFull;
    short* Vw    = Kw + nFull;       // transposed [BH][HS][T]

    conv_bf16<<<dim3((int)(nWq / 2048)), blk, 0, stream>>>(Wqkv, Wq_bf);
    conv_bf16<<<dim3((int)(nWp / 2048)), blk, 0, stream>>>(Wproj, Wp_bf);
    conv_bf16<<<dim3((int)(nFull / 2048)), blk, 0, stream>>>(x, S0);
    qkv_gemm<<<dim3(M_ / 128, N1_ / 128), blk, 0, stream>>>(S0, Wq_bf, bqkv, Qw, Kw, Vw);
    attn<<<dim3(T_ / 64, BH_), blk, 0, stream>>>(Qw, Kw, Vw, S0);
    proj_gemm<<<dim3(M_ / 128, C_ / 128), blk, 0, stream>>>(S0, Wp_bf, bproj, out);
  } else {
    // -------- per-batch fallback (25.2 MB ws) --------
    short* Wq_bf = (short*)d_ws;
    short* Wp_bf = Wq_bf + nWq;
    short* S0    = Wp_bf + nWp;      // x_bf, later Y (per batch)
    short* Qw    = S0 + nB;
    short* Kw    = Qw + nB;
    short* Vw    = Kw + nB;

    conv_bf16<<<dim3((int)(nWq / 2048)), blk, 0, stream>>>(Wqkv, Wq_bf);
    conv_bf16<<<dim3((int)(nWp / 2048)), blk, 0, stream>>>(Wproj, Wp_bf);
    for (int b = 0; b < B_; ++b) {
      const float* xb = x   + (size_t)b * nB;
      float*       ob = out + (size_t)b * nB;
      conv_bf16<<<dim3((int)(nB / 2048)), blk, 0, stream>>>(xb, S0);
      qkv_gemm<<<dim3(T_ / 128, N1_ / 128), blk, 0, stream>>>(S0, Wq_bf, bqkv, Qw, Kw, Vw);
      attn<<<dim3(T_ / 64, NH_), blk, 0, stream>>>(Qw, Kw, Vw, S0);
      proj_gemm<<<dim3(T_ / 128, C_ / 128), blk, 0, stream>>>(S0, Wp_bf, bproj, ob);
    }
  }
}